// Round 2
// baseline (95.099 us; speedup 1.0000x reference)
//
#include <hip/hip_runtime.h>
#include <hip/hip_bf16.h>

// Fused shift/roll/unfold/conv (all float32):
//   u[h,k,o,c] = x[c, h, (o+k-2)%14]   if 0 <= o+k-1 <= 13, else 0   (h valid)
//   r[h,k,o,l] = u[h,k,o,l] + u[h,k,(o-1)%14, 128+l]
//   y[i,n,o]   = sum_{j,k,l} r[n+j-1,k,o,l] * w[i,j,k,l]   (h=n+j-1 zero-padded)
//
// x: (256,14,14) f32, w: (256,3,3,128) f32, y: (256,14,14) f32.

#define RSTRIDE 132  // 128 + 4 pad: bank = (o*132+l)%32 = (o*4+l)%32 -> worst 2-way alias (free)

__global__ __launch_bounds__(256) void fused_shiftconv(
    const float* __restrict__ x,
    const float* __restrict__ w,
    float* __restrict__ out)
{
    __shared__ float r[3 * 3 * 14 * RSTRIDE];   // 66528 B -> <=2 blocks/CU by LDS
    const int n  = blockIdx.x;        // output row
    const int ib = blockIdx.y << 4;   // 16 output channels per block
    const int t  = threadIdx.x;

    // ---- Phase 1: materialize r slice for h = n-1..n+1 into LDS ----
    for (int e = t; e < 3 * 3 * 14 * 128; e += 256) {
        int l    = e & 127;
        int rest = e >> 7;            // (jj*3 + kk)*14 + o
        int o    = rest % 14;
        int kk   = (rest / 14) % 3;
        int jj   = rest / 42;
        int h    = n + jj - 1;
        float val = 0.f;
        if ((unsigned)h < 14u) {
            // B term: x[l, h, (o+kk-2)%14] if 0 <= o+kk-1 <= 13
            int wb = o + kk - 1;
            if ((unsigned)wb < 14u) {
                int widx = wb - 1; if (widx < 0) widx = 13;
                val += x[l * 196 + h * 14 + widx];
            }
            // A term: x[128+l, h, (v+kk-2)%14], v=(o-1)%14, if 0 <= v+kk-1 <= 13
            int v  = o - 1; if (v < 0) v = 13;
            int wa = v + kk - 1;
            if ((unsigned)wa < 14u) {
                int widx = wa - 1; if (widx < 0) widx = 13;
                val += x[(128 + l) * 196 + h * 14 + widx];
            }
        }
        r[rest * RSTRIDE + l] = val;
    }
    __syncthreads();

    // ---- Phase 2: one output per thread (224 active of 256) ----
    if (t < 224) {
        const int i = ib + (t / 14);
        const int o = t % 14;
        float acc = 0.f;
        const float* wp = w + i * 1152;   // w[i,:,:,:]
        #pragma unroll
        for (int jk = 0; jk < 9; ++jk) {
            const float* rp = &r[(jk * 14 + o) * RSTRIDE];
            const float* wq = wp + jk * 128;
            #pragma unroll 4
            for (int l = 0; l < 128; l += 8) {
                float4 w0 = *(const float4*)(wq + l);
                float4 w1 = *(const float4*)(wq + l + 4);
                float4 r0 = *(const float4*)(rp + l);     // ds_read_b128
                float4 r1 = *(const float4*)(rp + l + 4);
                acc += r0.x * w0.x;
                acc += r0.y * w0.y;
                acc += r0.z * w0.z;
                acc += r0.w * w0.w;
                acc += r1.x * w1.x;
                acc += r1.y * w1.y;
                acc += r1.z * w1.z;
                acc += r1.w * w1.w;
            }
        }
        out[(i * 14 + n) * 14 + o] = acc;
    }
}

extern "C" void kernel_launch(void* const* d_in, const int* in_sizes, int n_in,
                              void* d_out, int out_size, void* d_ws, size_t ws_size,
                              hipStream_t stream) {
    const float* x = (const float*)d_in[0];  // 256*14*14 = 50176
    const float* w = (const float*)d_in[1];  // 256*3*3*128 = 294912
    float* out = (float*)d_out;              // 50176
    dim3 grid(14, 16);  // n  x  (256/16 channel chunks)
    fused_shiftconv<<<grid, 256, 0, stream>>>(x, w, out);
}

// Round 3
// 84.191 us; speedup vs baseline: 1.1296x; 1.1296x over previous
//
#include <hip/hip_runtime.h>
#include <hip/hip_bf16.h>

// Fused shift/roll/unfold/conv (f32):
//   u[h,k,o,c] = x[c, h, widx(o+k-1)]  gated 0 <= o+k-1 < 14   (widx = wrap-decrement)
//   r[h,k,o,l] = u[..,l] + u'[..,(o-1)%14, 128+l]
//   y[i,n,o]   = sum_{j,k,l} r[n+j-1,k,o,l] * w[i,j,k,l]
//
// Block = 256 thr (4 waves), grid (14 n, 16 ig). Wave wv owns i = ig*16+wv*4 .. +3.
// Lane q-split: q = qi*256 + lane*4 (qi<4) plus tail q = 1024 + lane*2; q = jk*128+l.
//
// LDS: bufA = xs (256c x 42, stride 43) then lane-partials (224 rows x 66);
//      rs   = r2[jk*14+o][l]  (126 x 128).

__global__ __launch_bounds__(256) void fused_shiftconv(
    const float* __restrict__ x,    // (256,14,14)
    const float* __restrict__ w,    // (256,3,3,128) : i*1152 + (j*3+k)*128 + l
    float* __restrict__ out)        // (256,14,14)
{
    __shared__ __align__(16) float bufA[224 * 66];   // 14784 f (xs uses first 11008)
    __shared__ __align__(16) float rs[126 * 128];    // 16128 f

    const int n    = blockIdx.x;
    const int ig   = blockIdx.y;
    const int t    = threadIdx.x;
    const int lane = t & 63;
    const int wv   = t >> 6;

    // ---- w staging into registers (issued early; overlaps phase 1) ----
    const float* wbase = w + (ig * 16 + wv * 4) * 1152;
    float4 wq[4][4];
    float2 wt[4];
    #pragma unroll
    for (int ii = 0; ii < 4; ++ii) {
        const float* wp = wbase + ii * 1152;
        #pragma unroll
        for (int qi = 0; qi < 4; ++qi)
            wq[ii][qi] = *(const float4*)(wp + qi * 256 + lane * 4);
        wt[ii] = *(const float2*)(wp + 1024 + lane * 2);
    }

    // ---- 1a: xs[c][s] = x[c, n-1+s/14, s%14], 0 if h OOB. Coalesced global. ----
    for (int m = t; m < 256 * 42; m += 256) {
        int c  = m / 42;
        int s  = m - c * 42;
        int jj = s / 14;
        int wi = s - jj * 14;
        int h  = n - 1 + jj;
        float v = 0.f;
        if ((unsigned)h < 14u) v = x[c * 196 + h * 14 + wi];
        bufA[c * 43 + s] = v;
    }
    __syncthreads();

    // ---- 1b: rs[jk*14+o][l] = B + A  (wave-uniform o,jk -> no divergence) ----
    for (int e = t; e < 16128; e += 256) {
        int l    = e & 127;
        int rest = e >> 7;            // jk*14 + o
        int o    = rest % 14;
        int jk   = rest / 14;
        int j    = jk / 3;
        int k    = jk - j * 3;
        float val = 0.f;
        int wb = o + k - 1;
        if ((unsigned)wb < 14u) {
            int wxi = wb ? wb - 1 : 13;
            val += bufA[l * 43 + j * 14 + wxi];
        }
        int vv = o ? o - 1 : 13;
        int wa = vv + k - 1;
        if ((unsigned)wa < 14u) {
            int wxi = wa ? wa - 1 : 13;
            val += bufA[(128 + l) * 43 + j * 14 + wxi];
        }
        rs[rest * 128 + l] = val;
    }
    __syncthreads();

    // ---- 2: per o, per-lane partial dot over this lane's 18 q's, 4 i's ----
    const int rbase = ((lane >> 5) * 1792) + ((lane & 31) * 4);  // qi step +3584
    const int tbase = 8 * 1792 + lane * 2;
    const int prow  = wv * 56;       // + ii*14 + o  (row stride 66)
    #pragma unroll 2
    for (int o = 0; o < 14; ++o) {
        const int ro = o * 128;
        float4 r0 = *(const float4*)(rs + rbase + ro);
        float4 r1 = *(const float4*)(rs + rbase + 3584 + ro);
        float4 r2 = *(const float4*)(rs + rbase + 7168 + ro);
        float4 r3 = *(const float4*)(rs + rbase + 10752 + ro);
        float2 rt = *(const float2*)(rs + tbase + ro);
        #pragma unroll
        for (int ii = 0; ii < 4; ++ii) {
            float a;
            a  = r0.x * wq[ii][0].x + r0.y * wq[ii][0].y + r0.z * wq[ii][0].z + r0.w * wq[ii][0].w;
            a += r1.x * wq[ii][1].x + r1.y * wq[ii][1].y + r1.z * wq[ii][1].z + r1.w * wq[ii][1].w;
            a += r2.x * wq[ii][2].x + r2.y * wq[ii][2].y + r2.z * wq[ii][2].z + r2.w * wq[ii][2].w;
            a += r3.x * wq[ii][3].x + r3.y * wq[ii][3].y + r3.z * wq[ii][3].z + r3.w * wq[ii][3].w;
            a += rt.x * wt[ii].x + rt.y * wt[ii].y;
            bufA[(prow + ii * 14 + o) * 66 + lane] = a;
        }
    }
    __syncthreads();

    // ---- 3: reduce 64 lane-partials per output, write y ----
    if (t < 224) {
        // row = t = wv2*56 + ii*14 + o
        int wv2 = t / 56;
        int rem = t - wv2 * 56;
        int ii  = rem / 14;
        int o   = rem - ii * 14;
        const float* pr = bufA + t * 66;
        float s = 0.f;
        #pragma unroll
        for (int k2 = 0; k2 < 32; ++k2) {      // float2: 8B-aligned, <=4-way bank alias
            float2 v = *(const float2*)(pr + k2 * 2);
            s += v.x + v.y;
        }
        int i = ig * 16 + wv2 * 4 + ii;
        out[(i * 14 + n) * 14 + o] = s;
    }
}

extern "C" void kernel_launch(void* const* d_in, const int* in_sizes, int n_in,
                              void* d_out, int out_size, void* d_ws, size_t ws_size,
                              hipStream_t stream) {
    const float* x = (const float*)d_in[0];  // 256*14*14
    const float* w = (const float*)d_in[1];  // 256*3*3*128
    float* out = (float*)d_out;              // 256*14*14
    dim3 grid(14, 16);
    fused_shiftconv<<<grid, 256, 0, stream>>>(x, w, out);
}

// Round 4
// 62.822 us; speedup vs baseline: 1.5138x; 1.3402x over previous
//
#include <hip/hip_runtime.h>
#include <hip/hip_bf16.h>

// Fused shift/roll/unfold/conv (f32 in/out, bf16 LDS intermediate):
//   r[h,k,o,l] = gate_b(k,o)*x[l,h,widx_b(k,o)] + gate_a(k,o)*x[128+l,h,widx_a(k,o)]
//   y[i,n,o]   = sum_{j,k,l} r[n+j-1,k,o,l] * w[i,j,k,l]
//
// Grid (14 n, 32 ig), block 256 (4 waves). 8 output channels per block, 2 per wave.
// Phase 1: thread = (j,l): x rows -> registers -> 42 statically-indexed r values -> LDS (bf16).
// Phase 2: q-split across lanes (q = qi*256+lane*4, tail 1024+lane*2); w in registers.
// Phase 3: LDS partial reduce, 112 outputs/block.

__device__ __forceinline__ float bf2f(unsigned short u) {
    union { unsigned int i; float f; } c; c.i = ((unsigned int)u) << 16; return c.f;
}
__device__ __forceinline__ unsigned short f2bf(float f) {
    __hip_bfloat16 b = __float2bfloat16(f);   // RNE
    return *(unsigned short*)&b;
}

__global__ __launch_bounds__(256) void fused_shiftconv(
    const float* __restrict__ x,    // (256,14,14)
    const float* __restrict__ w,    // (256,3,3,128): i*1152 + (j*3+k)*128 + l
    float* __restrict__ out)        // (256,14,14)
{
    __shared__ __align__(16) unsigned short rs[126 * 128];  // 32256 B, bf16 r-slice
    __shared__ __align__(16) float parts[112 * 66];         // 29568 B lane-partials

    const int n    = blockIdx.x;
    const int ig   = blockIdx.y;          // 0..31, 8 i per block
    const int t    = threadIdx.x;
    const int lane = t & 63;
    const int wv   = t >> 6;

    // ---- w staging into registers (independent loads, overlap phase 1) ----
    const float* wbase = w + (ig * 8 + wv * 2) * 1152;
    float4 wq[2][4];
    float2 wt[2];
    #pragma unroll
    for (int ii = 0; ii < 2; ++ii) {
        const float* wp = wbase + ii * 1152;
        #pragma unroll
        for (int qi = 0; qi < 4; ++qi)
            wq[ii][qi] = *(const float4*)(wp + qi * 256 + lane * 4);
        wt[ii] = *(const float2*)(wp + 1024 + lane * 2);
    }

    // ---- Phase 1: build rs. Items: (j = t>>7, l = t&127) and, for t<128, (j=2, l=t). ----
    #pragma unroll
    for (int item = 0; item < 2; ++item) {
        int j, l;
        if (item == 0) { j = t >> 7; l = t & 127; }
        else           { if (t >= 128) break; j = 2; l = t; }

        const int h = n + j - 1;
        float xlo[14], xhi[14];
        if ((unsigned)h < 14u) {                    // wave-uniform branch
            const float* p0 = x + l * 196 + h * 14;
            const float* p1 = x + (128 + l) * 196 + h * 14;
            #pragma unroll
            for (int wi = 0; wi < 14; wi += 2) {
                float2 a = *(const float2*)(p0 + wi);
                float2 b = *(const float2*)(p1 + wi);
                xlo[wi] = a.x; xlo[wi + 1] = a.y;
                xhi[wi] = b.x; xhi[wi + 1] = b.y;
            }
        } else {
            #pragma unroll
            for (int wi = 0; wi < 14; ++wi) { xlo[wi] = 0.f; xhi[wi] = 0.f; }
        }
        // 42 (k,o) values, all indices compile-time after unroll
        #pragma unroll
        for (int k = 0; k < 3; ++k) {
            #pragma unroll
            for (int o = 0; o < 14; ++o) {
                float val = 0.f;
                const int wb = o + k - 1;                 // B-term gate/index
                if (wb >= 0 && wb < 14) val += xlo[wb ? wb - 1 : 13];
                const int v  = o ? o - 1 : 13;            // A-term gate/index
                const int wa = v + k - 1;
                if (wa >= 0 && wa < 14) val += xhi[wa ? wa - 1 : 13];
                rs[((j * 3 + k) * 14 + o) * 128 + l] = f2bf(val);
            }
        }
    }
    __syncthreads();

    // ---- Phase 2: per o, per-lane partial dots (18 q per lane, 2 i per wave) ----
    const int rbl   = (lane & 31) * 4;     // l base for qi chunks
    const int jkhi  = lane >> 5;           // 0/1: jk = qi*2 + jkhi
    const int prow0 = (wv * 2) * 14;       // partial row base (stride 66)
    #pragma unroll 2
    for (int o = 0; o < 14; ++o) {
        float rv[18];
        #pragma unroll
        for (int qi = 0; qi < 4; ++qi) {
            const int row = (qi * 2 + jkhi) * 14 + o;
            ushort4 u = *(const ushort4*)(rs + row * 128 + rbl);   // ds_read_b64
            rv[qi * 4 + 0] = bf2f(u.x);
            rv[qi * 4 + 1] = bf2f(u.y);
            rv[qi * 4 + 2] = bf2f(u.z);
            rv[qi * 4 + 3] = bf2f(u.w);
        }
        {
            const int rowt = 112 + o;
            ushort2 ut = *(const ushort2*)(rs + rowt * 128 + lane * 2);
            rv[16] = bf2f(ut.x);
            rv[17] = bf2f(ut.y);
        }
        #pragma unroll
        for (int ii = 0; ii < 2; ++ii) {
            float a;
            a  = rv[0]  * wq[ii][0].x + rv[1]  * wq[ii][0].y + rv[2]  * wq[ii][0].z + rv[3]  * wq[ii][0].w;
            a += rv[4]  * wq[ii][1].x + rv[5]  * wq[ii][1].y + rv[6]  * wq[ii][1].z + rv[7]  * wq[ii][1].w;
            a += rv[8]  * wq[ii][2].x + rv[9]  * wq[ii][2].y + rv[10] * wq[ii][2].z + rv[11] * wq[ii][2].w;
            a += rv[12] * wq[ii][3].x + rv[13] * wq[ii][3].y + rv[14] * wq[ii][3].z + rv[15] * wq[ii][3].w;
            a += rv[16] * wt[ii].x + rv[17] * wt[ii].y;
            parts[(prow0 + ii * 14 + o) * 66 + lane] = a;
        }
    }
    __syncthreads();

    // ---- Phase 3: reduce 64 lane-partials per output ----
    if (t < 112) {
        const float* pr = parts + t * 66;
        float s = 0.f;
        #pragma unroll
        for (int k2 = 0; k2 < 32; ++k2) {
            float2 v = *(const float2*)(pr + k2 * 2);
            s += v.x + v.y;
        }
        const int ii = t / 14;
        const int o  = t - ii * 14;
        const int i  = ig * 8 + ii;
        out[(i * 14 + n) * 14 + o] = s;
    }
}

extern "C" void kernel_launch(void* const* d_in, const int* in_sizes, int n_in,
                              void* d_out, int out_size, void* d_ws, size_t ws_size,
                              hipStream_t stream) {
    const float* x = (const float*)d_in[0];  // 256*14*14
    const float* w = (const float*)d_in[1];  // 256*3*3*128
    float* out = (float*)d_out;              // 256*14*14
    dim3 grid(14, 32);
    fused_shiftconv<<<grid, 256, 0, stream>>>(x, w, out);
}

// Round 5
// 61.049 us; speedup vs baseline: 1.5577x; 1.0290x over previous
//
#include <hip/hip_runtime.h>
#include <hip/hip_bf16.h>

// Fused shift/roll/unfold/conv (f32 in/out, bf16 LDS intermediate):
//   r[h,k,o,l] = gate_b(k,o)*x[l,h,widx_b(k,o)] + gate_a(k,o)*x[128+l,h,widx_a(k,o)]
//   y[i,n,o]   = sum_{j,k,l} r[n+j-1,k,o,l] * w[i,j,k,l]
//
// Grid (14 n, 16 ig) = 224 blocks (<= 256 CUs: single block-round).
// Block 512 thr (8 waves). 16 output channels per block, 2 per wave.
// Phase 1 (384 thr): thread=(j,l): x rows -> regs -> 42 static-index r values -> LDS bf16.
// Phase 2: q-split across lanes (q = qi*256+lane*4, tail 1024+lane*2); w in registers.
// Phase 3 (224 thr = 224 outputs): float4 partial reduce.

__device__ __forceinline__ float bf2f(unsigned short u) {
    union { unsigned int i; float f; } c; c.i = ((unsigned int)u) << 16; return c.f;
}
__device__ __forceinline__ unsigned short f2bf(float f) {
    __hip_bfloat16 b = __float2bfloat16(f);   // RNE
    return *(unsigned short*)&b;
}

#define PSTRIDE 68   // parts row stride (floats): 16B-aligned rows, banks (4*row+lane)%32

__global__ __launch_bounds__(512) void fused_shiftconv(
    const float* __restrict__ x,    // (256,14,14)
    const float* __restrict__ w,    // (256,3,3,128): i*1152 + (j*3+k)*128 + l
    float* __restrict__ out)        // (256,14,14)
{
    __shared__ __align__(16) unsigned short rs[126 * 128];    // 32256 B bf16 r-slice
    __shared__ __align__(16) float parts[224 * PSTRIDE];      // 60928 B lane-partials

    const int n    = blockIdx.x;
    const int ig   = blockIdx.y;          // 0..15, 16 i per block
    const int t    = threadIdx.x;
    const int lane = t & 63;
    const int wv   = t >> 6;              // 0..7

    // ---- w staging into registers (independent loads, overlap phase 1) ----
    const float* wbase = w + (ig * 16 + wv * 2) * 1152;
    float4 wq[2][4];
    float2 wt[2];
    #pragma unroll
    for (int ii = 0; ii < 2; ++ii) {
        const float* wp = wbase + ii * 1152;
        #pragma unroll
        for (int qi = 0; qi < 4; ++qi)
            wq[ii][qi] = *(const float4*)(wp + qi * 256 + lane * 4);
        wt[ii] = *(const float2*)(wp + 1024 + lane * 2);
    }

    // ---- Phase 1: build rs (384 threads; thread = (j = t>>7, l = t&127)) ----
    if (t < 384) {
        const int j = t >> 7;
        const int l = t & 127;
        const int h = n + j - 1;
        float xlo[14], xhi[14];
        if ((unsigned)h < 14u) {                    // wave-uniform branch
            const float* p0 = x + l * 196 + h * 14;
            const float* p1 = x + (128 + l) * 196 + h * 14;
            #pragma unroll
            for (int wi = 0; wi < 14; wi += 2) {
                float2 a = *(const float2*)(p0 + wi);
                float2 b = *(const float2*)(p1 + wi);
                xlo[wi] = a.x; xlo[wi + 1] = a.y;
                xhi[wi] = b.x; xhi[wi + 1] = b.y;
            }
        } else {
            #pragma unroll
            for (int wi = 0; wi < 14; ++wi) { xlo[wi] = 0.f; xhi[wi] = 0.f; }
        }
        // 42 (k,o) values, all indices compile-time after unroll
        #pragma unroll
        for (int k = 0; k < 3; ++k) {
            #pragma unroll
            for (int o = 0; o < 14; ++o) {
                float val = 0.f;
                const int wb = o + k - 1;                 // B-term gate/index
                if (wb >= 0 && wb < 14) val += xlo[wb ? wb - 1 : 13];
                const int v  = o ? o - 1 : 13;            // A-term gate/index
                const int wa = v + k - 1;
                if (wa >= 0 && wa < 14) val += xhi[wa ? wa - 1 : 13];
                rs[((j * 3 + k) * 14 + o) * 128 + l] = f2bf(val);
            }
        }
    }
    __syncthreads();

    // ---- Phase 2: per o, per-lane partial dots (18 q per lane, 2 i per wave) ----
    const int rbl   = (lane & 31) * 4;     // l base for qi chunks
    const int jkhi  = lane >> 5;           // 0/1: jk = qi*2 + jkhi
    const int prow0 = wv * 28;             // partial row base (stride PSTRIDE)
    #pragma unroll 2
    for (int o = 0; o < 14; ++o) {
        float rv[18];
        #pragma unroll
        for (int qi = 0; qi < 4; ++qi) {
            const int row = (qi * 2 + jkhi) * 14 + o;
            ushort4 u = *(const ushort4*)(rs + row * 128 + rbl);   // ds_read_b64
            rv[qi * 4 + 0] = bf2f(u.x);
            rv[qi * 4 + 1] = bf2f(u.y);
            rv[qi * 4 + 2] = bf2f(u.z);
            rv[qi * 4 + 3] = bf2f(u.w);
        }
        {
            const int rowt = 112 + o;
            ushort2 ut = *(const ushort2*)(rs + rowt * 128 + lane * 2);
            rv[16] = bf2f(ut.x);
            rv[17] = bf2f(ut.y);
        }
        #pragma unroll
        for (int ii = 0; ii < 2; ++ii) {
            float a;
            a  = rv[0]  * wq[ii][0].x + rv[1]  * wq[ii][0].y + rv[2]  * wq[ii][0].z + rv[3]  * wq[ii][0].w;
            a += rv[4]  * wq[ii][1].x + rv[5]  * wq[ii][1].y + rv[6]  * wq[ii][1].z + rv[7]  * wq[ii][1].w;
            a += rv[8]  * wq[ii][2].x + rv[9]  * wq[ii][2].y + rv[10] * wq[ii][2].z + rv[11] * wq[ii][2].w;
            a += rv[12] * wq[ii][3].x + rv[13] * wq[ii][3].y + rv[14] * wq[ii][3].z + rv[15] * wq[ii][3].w;
            a += rv[16] * wt[ii].x + rv[17] * wt[ii].y;
            parts[(prow0 + ii * 14 + o) * PSTRIDE + lane] = a;
        }
    }
    __syncthreads();

    // ---- Phase 3: reduce 64 lane-partials per output (224 threads = 224 outputs) ----
    if (t < 224) {
        const float* pr = parts + t * PSTRIDE;   // 272-byte row offset: 16B-aligned
        float s0 = 0.f, s1 = 0.f;
        #pragma unroll
        for (int k2 = 0; k2 < 16; k2 += 2) {
            float4 v0 = *(const float4*)(pr + k2 * 4);
            float4 v1 = *(const float4*)(pr + k2 * 4 + 4);
            s0 += v0.x + v0.y + v0.z + v0.w;
            s1 += v1.x + v1.y + v1.z + v1.w;
        }
        const int wv2 = t / 28;
        const int rem = t - wv2 * 28;
        const int ii  = rem / 14;
        const int o   = rem - ii * 14;
        const int i   = ig * 16 + wv2 * 2 + ii;
        out[(i * 14 + n) * 14 + o] = s0 + s1;
    }
}

extern "C" void kernel_launch(void* const* d_in, const int* in_sizes, int n_in,
                              void* d_out, int out_size, void* d_ws, size_t ws_size,
                              hipStream_t stream) {
    const float* x = (const float*)d_in[0];  // 256*14*14
    const float* w = (const float*)d_in[1];  // 256*3*3*128
    float* out = (float*)d_out;              // 256*14*14
    dim3 grid(14, 16);
    fused_shiftconv<<<grid, 512, 0, stream>>>(x, w, out);
}